// Round 2
// baseline (1306.720 us; speedup 1.0000x reference)
//
#include <hip/hip_runtime.h>
#include <math.h>

// LightGCN-style propagation on MI355X.
// Strategy: build CSR (both directions) on-device each launch, then each
// propagation layer is a pure gather (wave-per-row, lane-per-dim) with the
// L2-normalization fused into the epilogue via wave shuffle reduction.

__global__ void count_deg_kernel(const int* __restrict__ eu, const int* __restrict__ ei,
                                 int* __restrict__ deg, int E, int NU) {
    int e = blockIdx.x * blockDim.x + threadIdx.x;
    if (e >= E) return;
    atomicAdd(&deg[eu[e]], 1);
    atomicAdd(&deg[NU + ei[e]], 1);
}

__global__ void bump_kernel(const int* __restrict__ deg, int* __restrict__ offs,
                            int* __restrict__ total, int n) {
    int i = blockIdx.x * blockDim.x + threadIdx.x;
    if (i >= n) return;
    // Row order within the CSR slot array is irrelevant; bump allocation
    // replaces a full prefix-sum. LLVM's atomic optimizer wave-coalesces this.
    offs[i] = atomicAdd(total, deg[i]);
}

__global__ void fill_csr_kernel(const int* __restrict__ eu, const int* __restrict__ ei,
                                const int* __restrict__ deg, const int* __restrict__ offs,
                                int* __restrict__ cursor, int2* __restrict__ csr,
                                int E, int NU) {
    int e = blockIdx.x * blockDim.x + threadIdx.x;
    if (e >= E) return;
    int u = eu[e], it = ei[e];
    float w = rsqrtf((float)deg[u] * (float)deg[NU + it]);
    int iw = __float_as_int(w);
    int su = offs[u] + atomicAdd(&cursor[u], 1);
    csr[su] = make_int2(it, iw);          // user-row entries hold item src
    int si = offs[NU + it] + atomicAdd(&cursor[NU + it], 1);
    csr[si] = make_int2(u, iw);           // item-row entries hold user src
}

// One wave per destination row; lane = feature dim (D == 64 == wavefront).
// dst[row] = l2norm( sum_e w_e * src[src_e] )
__global__ void prop_kernel(const float* __restrict__ src_feat, float* __restrict__ dst_feat,
                            const int* __restrict__ offs, const int* __restrict__ deg,
                            const int2* __restrict__ csr, int nrows, int row_base) {
    int wave = (blockIdx.x * blockDim.x + threadIdx.x) >> 6;
    int lane = threadIdx.x & 63;
    if (wave >= nrows) return;
    int r = __builtin_amdgcn_readfirstlane(row_base + wave);
    int start = __builtin_amdgcn_readfirstlane(offs[r]);
    int dcount = __builtin_amdgcn_readfirstlane(deg[r]);
    float acc = 0.f;
    for (int j = 0; j < dcount; ++j) {
        int2 ent = csr[start + j];
        acc = fmaf(__int_as_float(ent.y), src_feat[(size_t)ent.x * 64 + lane], acc);
    }
    // fused L2 norm across the 64 lanes (one full row per wave)
    float ss = acc * acc;
    #pragma unroll
    for (int m = 32; m >= 1; m >>= 1) ss += __shfl_xor(ss, m, 64);
    float scale = 1.f / fmaxf(sqrtf(ss), 1e-12f);
    dst_feat[(size_t)wave * 64 + lane] = acc * scale;
}

__global__ void out_init_kernel(const float* __restrict__ uf, const float* __restrict__ itf,
                                const int* __restrict__ users, const int* __restrict__ pos,
                                const int* __restrict__ neg, float* __restrict__ out, int B) {
    int t = blockIdx.x * blockDim.x + threadIdx.x;
    if (t >= 3 * B * 64) return;
    int lane = t & 63;
    int row = t >> 6;
    int seg = row / B, b = row - seg * B;
    const float* src; int idx;
    if (seg == 0)      { src = uf;  idx = users[b]; }
    else if (seg == 1) { src = itf; idx = pos[b]; }
    else               { src = itf; idx = neg[b]; }
    out[t] = src[(size_t)idx * 64 + lane];
}

__global__ void out_accum_kernel(const float* __restrict__ uh, const float* __restrict__ ih,
                                 const int* __restrict__ users, const int* __restrict__ pos,
                                 const int* __restrict__ neg, float* __restrict__ out,
                                 float coef, int B) {
    int t = blockIdx.x * blockDim.x + threadIdx.x;
    if (t >= 3 * B * 64) return;
    int lane = t & 63;
    int row = t >> 6;
    int seg = row / B, b = row - seg * B;
    const float* src; int idx;
    if (seg == 0)      { src = uh; idx = users[b]; }
    else if (seg == 1) { src = ih; idx = pos[b]; }
    else               { src = ih; idx = neg[b]; }
    out[t] += coef * src[(size_t)idx * 64 + lane];
}

extern "C" void kernel_launch(void* const* d_in, const int* in_sizes, int n_in,
                              void* d_out, int out_size, void* d_ws, size_t ws_size,
                              hipStream_t stream) {
    const float* user_feat = (const float*)d_in[0];
    const float* item_feat = (const float*)d_in[1];
    const int* edge_u = (const int*)d_in[2];
    const int* edge_i = (const int*)d_in[3];
    const int* users  = (const int*)d_in[4];
    const int* pos    = (const int*)d_in[5];
    const int* neg    = (const int*)d_in[6];
    float* out = (float*)d_out;

    const int D = 64;
    const int NU = in_sizes[0] / D;
    const int NI = in_sizes[1] / D;
    const int E  = in_sizes[2];
    const int B  = in_sizes[4];
    const int NT = NU + NI;

    char* ws = (char*)d_ws;
    size_t off = 0;
    auto alloc = [&](size_t bytes) -> void* {
        void* p = ws + off;
        off += bytes;
        off = (off + 255) & ~(size_t)255;
        return p;
    };
    // Zero-zone (deg, cursor, total) must be contiguous for one memset.
    size_t zbytes = (size_t)(2 * (size_t)NT + 1) * 4;
    char* zbase = (char*)alloc(zbytes);
    int* deg    = (int*)zbase;
    int* cursor = deg + NT;
    int* total  = cursor + NT;
    int*  offs = (int*)alloc((size_t)NT * 4);
    int2* csr  = (int2*)alloc((size_t)2 * E * 8);
    float* uhA = (float*)alloc((size_t)NU * D * 4);
    float* uhB = (float*)alloc((size_t)NU * D * 4);
    float* ihA = (float*)alloc((size_t)NI * D * 4);
    float* ihB = (float*)alloc((size_t)NI * D * 4);

    hipMemsetAsync(zbase, 0, zbytes, stream);

    int tb = 256;
    count_deg_kernel<<<(E + tb - 1) / tb, tb, 0, stream>>>(edge_u, edge_i, deg, E, NU);
    bump_kernel<<<(NT + tb - 1) / tb, tb, 0, stream>>>(deg, offs, total, NT);
    fill_csr_kernel<<<(E + tb - 1) / tb, tb, 0, stream>>>(edge_u, edge_i, deg, offs,
                                                          cursor, csr, E, NU);

    int out_threads = 3 * B * 64;
    out_init_kernel<<<(out_threads + tb - 1) / tb, tb, 0, stream>>>(
        user_feat, item_feat, users, pos, neg, out, B);

    const float* uc = user_feat;
    const float* ic = item_feat;
    float* ubuf[2] = {uhA, uhB};
    float* ibuf[2] = {ihA, ihB};

    for (int k = 0; k < 3; ++k) {
        float* ud = ubuf[k & 1];
        float* id = ibuf[k & 1];
        // new_ih = segsum over edges into items of w * uh_old[src user]
        prop_kernel<<<(NI + 3) / 4, tb, 0, stream>>>(uc, id, offs, deg, csr, NI, NU);
        // new_uh = segsum over edges into users of w * ih_old[src item]
        prop_kernel<<<(NU + 3) / 4, tb, 0, stream>>>(ic, ud, offs, deg, csr, NU, 0);
        out_accum_kernel<<<(out_threads + tb - 1) / tb, tb, 0, stream>>>(
            ud, id, users, pos, neg, out, 1.0f / (float)(k + 1), B);
        uc = ud;
        ic = id;
    }
}

// Round 3
// 887.756 us; speedup vs baseline: 1.4719x; 1.4719x over previous
//
#include <hip/hip_runtime.h>
#include <math.h>

// LightGCN propagation, round 3.
// - CSR entries are 4B (src index only); edge weight recomputed from the
//   L2-resident degree array in the gather kernels.
// - Propagation: one wave per dest row, 4 groups of 16 lanes, each group
//   walks a different edge with float4 loads, unrolled x2 => 8 independent
//   256B gathers in flight per wave (breaks the dependent-load latency chain).
// - Layer 3 is computed only at the 3*B sampled rows, fused into d_out.

__global__ void count_deg_kernel(const int* __restrict__ eu, const int* __restrict__ ei,
                                 int* __restrict__ deg, int E, int NU) {
    int e = blockIdx.x * blockDim.x + threadIdx.x;
    if (e >= E) return;
    atomicAdd(&deg[eu[e]], 1);
    atomicAdd(&deg[NU + ei[e]], 1);
}

__global__ void bump_kernel(const int* __restrict__ deg, int* __restrict__ offs,
                            int* __restrict__ total, int n) {
    int i = blockIdx.x * blockDim.x + threadIdx.x;
    if (i >= n) return;
    offs[i] = atomicAdd(total, deg[i]);   // bump alloc; row order irrelevant
}

__global__ void fill_csr_kernel(const int* __restrict__ eu, const int* __restrict__ ei,
                                const int* __restrict__ offs, int* __restrict__ cursor,
                                int* __restrict__ csr, int E, int NU) {
    int e = blockIdx.x * blockDim.x + threadIdx.x;
    if (e >= E) return;
    int u = eu[e], it = ei[e];
    int su = offs[u] + atomicAdd(&cursor[u], 1);
    csr[su] = it;                          // user-row entries hold item src
    int si = offs[NU + it] + atomicAdd(&cursor[NU + it], 1);
    csr[si] = u;                           // item-row entries hold user src
}

// Shared gather body: compute l2-normalized weighted sum for dest row r.
// g = lane>>4 selects one of 4 edge streams; l16 = lane&15 covers the row
// in float4 chunks. Returns the normalized row fragment in `a` (all groups
// hold identical copies after the cross-group reduce).
__device__ __forceinline__ float4 gather_row(const float* __restrict__ sfeat,
                                             const int* __restrict__ deg,
                                             const int* __restrict__ csr,
                                             int start, int dcount, int sdb,
                                             int g, int l16) {
    float degr = (float)dcount;
    float4 a0 = make_float4(0.f, 0.f, 0.f, 0.f);
    float4 a1 = make_float4(0.f, 0.f, 0.f, 0.f);
    int j = g;
    for (; j + 4 < dcount; j += 8) {
        int s0 = csr[start + j];
        int s1 = csr[start + j + 4];
        float w0 = rsqrtf(degr * (float)deg[sdb + s0]);
        float w1 = rsqrtf(degr * (float)deg[sdb + s1]);
        float4 f0 = *(const float4*)(sfeat + (size_t)s0 * 64 + l16 * 4);
        float4 f1 = *(const float4*)(sfeat + (size_t)s1 * 64 + l16 * 4);
        a0.x = fmaf(w0, f0.x, a0.x); a0.y = fmaf(w0, f0.y, a0.y);
        a0.z = fmaf(w0, f0.z, a0.z); a0.w = fmaf(w0, f0.w, a0.w);
        a1.x = fmaf(w1, f1.x, a1.x); a1.y = fmaf(w1, f1.y, a1.y);
        a1.z = fmaf(w1, f1.z, a1.z); a1.w = fmaf(w1, f1.w, a1.w);
    }
    if (j < dcount) {
        int s0 = csr[start + j];
        float w0 = rsqrtf(degr * (float)deg[sdb + s0]);
        float4 f0 = *(const float4*)(sfeat + (size_t)s0 * 64 + l16 * 4);
        a0.x = fmaf(w0, f0.x, a0.x); a0.y = fmaf(w0, f0.y, a0.y);
        a0.z = fmaf(w0, f0.z, a0.z); a0.w = fmaf(w0, f0.w, a0.w);
    }
    float4 a = make_float4(a0.x + a1.x, a0.y + a1.y, a0.z + a1.z, a0.w + a1.w);
    #pragma unroll
    for (int m = 16; m <= 32; m <<= 1) {
        a.x += __shfl_xor(a.x, m, 64);
        a.y += __shfl_xor(a.y, m, 64);
        a.z += __shfl_xor(a.z, m, 64);
        a.w += __shfl_xor(a.w, m, 64);
    }
    float ss = a.x * a.x + a.y * a.y + a.z * a.z + a.w * a.w;
    #pragma unroll
    for (int m = 1; m <= 8; m <<= 1) ss += __shfl_xor(ss, m, 64);
    float scale = 1.f / fmaxf(sqrtf(ss), 1e-12f);
    a.x *= scale; a.y *= scale; a.z *= scale; a.w *= scale;
    return a;
}

// One dispatch covers both directions: rows [0,NU) are users (gather from
// items), rows [NU,NT) are items (gather from users).
__global__ void prop_both_kernel(const float* __restrict__ uc, const float* __restrict__ ic,
                                 float* __restrict__ ud, float* __restrict__ id,
                                 const int* __restrict__ offs, const int* __restrict__ deg,
                                 const int* __restrict__ csr, int NU, int NT) {
    int wave = blockIdx.x * (blockDim.x >> 6) + (threadIdx.x >> 6);
    if (wave >= NT) return;
    int lane = threadIdx.x & 63;
    int g = lane >> 4, l16 = lane & 15;
    int r = __builtin_amdgcn_readfirstlane(wave);
    const float* sfeat;
    float* dst;
    int sdb;
    if (r < NU) { sfeat = ic; dst = ud + (size_t)r * 64; sdb = NU; }
    else        { sfeat = uc; dst = id + (size_t)(r - NU) * 64; sdb = 0; }
    int start  = __builtin_amdgcn_readfirstlane(offs[r]);
    int dcount = __builtin_amdgcn_readfirstlane(deg[r]);
    float4 a = gather_row(sfeat, deg, csr, start, dcount, sdb, g, l16);
    if (g == 0) *(float4*)(dst + l16 * 4) = a;
}

// Layer 3: only the 3*B sampled rows are ever read -> compute them directly
// into d_out (+= coef * l2norm(segsum)).
__global__ void last_layer_kernel(const float* __restrict__ uc, const float* __restrict__ ic,
                                  const int* __restrict__ users, const int* __restrict__ pos,
                                  const int* __restrict__ neg,
                                  const int* __restrict__ offs, const int* __restrict__ deg,
                                  const int* __restrict__ csr, float* __restrict__ out,
                                  int NU, int B, float coef) {
    int wave = blockIdx.x * (blockDim.x >> 6) + (threadIdx.x >> 6);
    if (wave >= 3 * B) return;
    int lane = threadIdx.x & 63;
    int g = lane >> 4, l16 = lane & 15;
    int seg = wave / B, b = wave - seg * B;
    int r, sdb;
    const float* sfeat;
    if (seg == 0)      { r = users[b];    sfeat = ic; sdb = NU; }
    else if (seg == 1) { r = NU + pos[b]; sfeat = uc; sdb = 0; }
    else               { r = NU + neg[b]; sfeat = uc; sdb = 0; }
    r = __builtin_amdgcn_readfirstlane(r);
    int start  = __builtin_amdgcn_readfirstlane(offs[r]);
    int dcount = __builtin_amdgcn_readfirstlane(deg[r]);
    float4 a = gather_row(sfeat, deg, csr, start, dcount, sdb, g, l16);
    if (g == 0) {
        float4* o = (float4*)(out + (size_t)wave * 64 + l16 * 4);
        float4 ov = *o;
        ov.x += coef * a.x; ov.y += coef * a.y;
        ov.z += coef * a.z; ov.w += coef * a.w;
        *o = ov;
    }
}

__global__ void out_init_kernel(const float* __restrict__ uf, const float* __restrict__ itf,
                                const int* __restrict__ users, const int* __restrict__ pos,
                                const int* __restrict__ neg, float* __restrict__ out, int B) {
    int t = blockIdx.x * blockDim.x + threadIdx.x;
    if (t >= 3 * B * 64) return;
    int lane = t & 63;
    int row = t >> 6;
    int seg = row / B, b = row - seg * B;
    const float* src; int idx;
    if (seg == 0)      { src = uf;  idx = users[b]; }
    else if (seg == 1) { src = itf; idx = pos[b]; }
    else               { src = itf; idx = neg[b]; }
    out[t] = src[(size_t)idx * 64 + lane];
}

__global__ void out_accum_kernel(const float* __restrict__ uh, const float* __restrict__ ih,
                                 const int* __restrict__ users, const int* __restrict__ pos,
                                 const int* __restrict__ neg, float* __restrict__ out,
                                 float coef, int B) {
    int t = blockIdx.x * blockDim.x + threadIdx.x;
    if (t >= 3 * B * 64) return;
    int lane = t & 63;
    int row = t >> 6;
    int seg = row / B, b = row - seg * B;
    const float* src; int idx;
    if (seg == 0)      { src = uh; idx = users[b]; }
    else if (seg == 1) { src = ih; idx = pos[b]; }
    else               { src = ih; idx = neg[b]; }
    out[t] += coef * src[(size_t)idx * 64 + lane];
}

extern "C" void kernel_launch(void* const* d_in, const int* in_sizes, int n_in,
                              void* d_out, int out_size, void* d_ws, size_t ws_size,
                              hipStream_t stream) {
    const float* user_feat = (const float*)d_in[0];
    const float* item_feat = (const float*)d_in[1];
    const int* edge_u = (const int*)d_in[2];
    const int* edge_i = (const int*)d_in[3];
    const int* users  = (const int*)d_in[4];
    const int* pos    = (const int*)d_in[5];
    const int* neg    = (const int*)d_in[6];
    float* out = (float*)d_out;

    const int D = 64;
    const int NU = in_sizes[0] / D;
    const int NI = in_sizes[1] / D;
    const int E  = in_sizes[2];
    const int B  = in_sizes[4];
    const int NT = NU + NI;

    char* ws = (char*)d_ws;
    size_t off = 0;
    auto alloc = [&](size_t bytes) -> void* {
        void* p = ws + off;
        off += bytes;
        off = (off + 255) & ~(size_t)255;
        return p;
    };
    // Zero-zone (deg, cursor, total) contiguous for one async memset.
    size_t zbytes = (size_t)(2 * (size_t)NT + 1) * 4;
    char* zbase = (char*)alloc(zbytes);
    int* deg    = (int*)zbase;
    int* cursor = deg + NT;
    int* total  = cursor + NT;
    int* offs = (int*)alloc((size_t)NT * 4);
    int* csr  = (int*)alloc((size_t)2 * E * 4);
    float* uhA = (float*)alloc((size_t)NU * D * 4);
    float* uhB = (float*)alloc((size_t)NU * D * 4);
    float* ihA = (float*)alloc((size_t)NI * D * 4);
    float* ihB = (float*)alloc((size_t)NI * D * 4);

    hipMemsetAsync(zbase, 0, zbytes, stream);

    const int tb = 256;
    count_deg_kernel<<<(E + tb - 1) / tb, tb, 0, stream>>>(edge_u, edge_i, deg, E, NU);
    bump_kernel<<<(NT + tb - 1) / tb, tb, 0, stream>>>(deg, offs, total, NT);
    fill_csr_kernel<<<(E + tb - 1) / tb, tb, 0, stream>>>(edge_u, edge_i, offs,
                                                          cursor, csr, E, NU);

    int out_threads = 3 * B * 64;
    out_init_kernel<<<(out_threads + tb - 1) / tb, tb, 0, stream>>>(
        user_feat, item_feat, users, pos, neg, out, B);

    // Layer 1
    prop_both_kernel<<<(NT + 3) / 4, tb, 0, stream>>>(user_feat, item_feat, uhA, ihA,
                                                      offs, deg, csr, NU, NT);
    out_accum_kernel<<<(out_threads + tb - 1) / tb, tb, 0, stream>>>(
        uhA, ihA, users, pos, neg, out, 1.0f, B);
    // Layer 2
    prop_both_kernel<<<(NT + 3) / 4, tb, 0, stream>>>(uhA, ihA, uhB, ihB,
                                                      offs, deg, csr, NU, NT);
    out_accum_kernel<<<(out_threads + tb - 1) / tb, tb, 0, stream>>>(
        uhB, ihB, users, pos, neg, out, 0.5f, B);
    // Layer 3: fused, only sampled rows
    last_layer_kernel<<<(3 * B + 3) / 4, tb, 0, stream>>>(
        uhB, ihB, users, pos, neg, offs, deg, csr, out, NU, B, 1.0f / 3.0f);
}